// Round 1
// baseline (823.420 us; speedup 1.0000x reference)
//
#include <hip/hip_runtime.h>
#include <math.h>

#define N_TOK 4096
#define DM 512

// ---------------------------------------------------------------------------
// Tiled fp32 GEMM: C[m,n] = scale * sum_k A[m,k] * Bop[k,n]
// TRANS_B=1: Bop[k,n] = B[n*K+k]   (B row-major [N,K] -> C = A*B^T)
// TRANS_B=0: Bop[k,n] = B[k*N+n]   (B row-major [K,N] -> C = A*B)
// 64x64 tile, 256 threads, 4x4 microtile, BK=16. All dims divisible by 64/16.
// ---------------------------------------------------------------------------
template <int TRANS_B>
__global__ __launch_bounds__(256) void gemm_kernel(const float* __restrict__ A,
                                                   const float* __restrict__ B,
                                                   float* __restrict__ C, int M,
                                                   int N, int K, float scale) {
  __shared__ float As[16][68];
  __shared__ float Bs[16][68];
  const int t = threadIdx.x;
  const int tx = t & 15;
  const int ty = t >> 4;
  const int bm = blockIdx.y * 64;
  const int bn = blockIdx.x * 64;

  float acc[4][4] = {};

  for (int k0 = 0; k0 < K; k0 += 16) {
    {
      int m = t >> 2;
      int kk = (t & 3) * 4;
      const float4 v = *(const float4*)(A + (size_t)(bm + m) * K + k0 + kk);
      As[kk + 0][m] = v.x;
      As[kk + 1][m] = v.y;
      As[kk + 2][m] = v.z;
      As[kk + 3][m] = v.w;
    }
    if (TRANS_B) {
      int n = t >> 2;
      int kk = (t & 3) * 4;
      const float4 v = *(const float4*)(B + (size_t)(bn + n) * K + k0 + kk);
      Bs[kk + 0][n] = v.x;
      Bs[kk + 1][n] = v.y;
      Bs[kk + 2][n] = v.z;
      Bs[kk + 3][n] = v.w;
    } else {
      int kk = t >> 4;
      int n4 = (t & 15) * 4;
      const float4 v = *(const float4*)(B + (size_t)(k0 + kk) * N + bn + n4);
      *(float4*)&Bs[kk][n4] = v;
    }
    __syncthreads();
#pragma unroll
    for (int k = 0; k < 16; ++k) {
      float a[4], b[4];
#pragma unroll
      for (int i = 0; i < 4; ++i) a[i] = As[k][ty * 4 + i];
#pragma unroll
      for (int j = 0; j < 4; ++j) b[j] = Bs[k][tx * 4 + j];
#pragma unroll
      for (int i = 0; i < 4; ++i)
#pragma unroll
        for (int j = 0; j < 4; ++j) acc[i][j] = fmaf(a[i], b[j], acc[i][j]);
    }
    __syncthreads();
  }
#pragma unroll
  for (int i = 0; i < 4; ++i) {
    float4 v;
    v.x = acc[i][0] * scale;
    v.y = acc[i][1] * scale;
    v.z = acc[i][2] * scale;
    v.w = acc[i][3] * scale;
    *(float4*)(C + (size_t)(bm + ty * 4 + i) * N + bn + tx * 4) = v;
  }
}

// ---------------------------------------------------------------------------
// sigma[i] = clip(dot(x[i,:], Ws), 0.001, 1.0). One wave per row.
// ---------------------------------------------------------------------------
__global__ __launch_bounds__(256) void sigma_kernel(const float* __restrict__ x,
                                                    const float* __restrict__ Ws,
                                                    float* __restrict__ sigma) {
  const int wave = threadIdx.x >> 6;
  const int lane = threadIdx.x & 63;
  const int row = blockIdx.x * 4 + wave;
  const float4* xr = (const float4*)(x + (size_t)row * DM);
  const float4* w = (const float4*)Ws;
  float s = 0.f;
#pragma unroll
  for (int r = 0; r < 2; ++r) {
    float4 a = xr[lane + 64 * r];
    float4 b = w[lane + 64 * r];
    s += a.x * b.x + a.y * b.y + a.z * b.z + a.w * b.w;
  }
#pragma unroll
  for (int off = 32; off > 0; off >>= 1) s += __shfl_down(s, off);
  if (lane == 0) sigma[row] = fminf(fmaxf(s, 0.001f), 1.0f);
}

// ---------------------------------------------------------------------------
// In-place row softmax on S [N_TOK x N_TOK]; one block (256 thr) per row,
// 16 elements per thread held in registers (float4 x4).
// ---------------------------------------------------------------------------
__global__ __launch_bounds__(256) void softmax_kernel(float* __restrict__ S) {
  __shared__ float red[256];
  const int t = threadIdx.x;
  float* Srow = S + (size_t)blockIdx.x * N_TOK;
  float4 v[4];
  float m = -INFINITY;
#pragma unroll
  for (int r = 0; r < 4; ++r) {
    v[r] = *(float4*)&Srow[r * 1024 + t * 4];
    m = fmaxf(m, fmaxf(fmaxf(v[r].x, v[r].y), fmaxf(v[r].z, v[r].w)));
  }
  red[t] = m;
  __syncthreads();
  for (int off = 128; off > 0; off >>= 1) {
    if (t < off) red[t] = fmaxf(red[t], red[t + off]);
    __syncthreads();
  }
  m = red[0];
  __syncthreads();
  float sum = 0.f;
#pragma unroll
  for (int r = 0; r < 4; ++r) {
    v[r].x = __expf(v[r].x - m);
    v[r].y = __expf(v[r].y - m);
    v[r].z = __expf(v[r].z - m);
    v[r].w = __expf(v[r].w - m);
    sum += v[r].x + v[r].y + v[r].z + v[r].w;
  }
  red[t] = sum;
  __syncthreads();
  for (int off = 128; off > 0; off >>= 1) {
    if (t < off) red[t] += red[t + off];
    __syncthreads();
  }
  const float inv = 1.0f / red[0];
#pragma unroll
  for (int r = 0; r < 4; ++r) {
    v[r].x *= inv;
    v[r].y *= inv;
    v[r].z *= inv;
    v[r].w *= inv;
    *(float4*)&Srow[r * 1024 + t * 4] = v[r];
  }
}

// ---------------------------------------------------------------------------
// P[i,j] = g / (sum_j g + 1e-8),  g = exp(-0.5*((i-j)/sig)^2) / sqrt(2*pi*sig)
// One block per row i.
// ---------------------------------------------------------------------------
__global__ __launch_bounds__(256) void p_kernel(const float* __restrict__ sigma,
                                                float* __restrict__ P) {
  __shared__ float red[256];
  const int i = blockIdx.x;
  const int t = threadIdx.x;
  const float sg = sigma[i];
  const float inv2 = -0.5f / (sg * sg);
  const float c = rsqrtf(6.283185307179586f * sg);
  float4 g[4];
  float sum = 0.f;
#pragma unroll
  for (int r = 0; r < 4; ++r) {
    int j = r * 1024 + t * 4;
    float d0 = (float)(i - j);
    float d1 = (float)(i - j - 1);
    float d2 = (float)(i - j - 2);
    float d3 = (float)(i - j - 3);
    g[r].x = __expf(inv2 * d0 * d0) * c;
    g[r].y = __expf(inv2 * d1 * d1) * c;
    g[r].z = __expf(inv2 * d2 * d2) * c;
    g[r].w = __expf(inv2 * d3 * d3) * c;
    sum += g[r].x + g[r].y + g[r].z + g[r].w;
  }
  red[t] = sum;
  __syncthreads();
  for (int off = 128; off > 0; off >>= 1) {
    if (t < off) red[t] += red[t + off];
    __syncthreads();
  }
  const float inv = 1.0f / (red[0] + 1e-8f);
  float* Prow = P + (size_t)i * N_TOK;
#pragma unroll
  for (int r = 0; r < 4; ++r) {
    g[r].x *= inv;
    g[r].y *= inv;
    g[r].z *= inv;
    g[r].w *= inv;
    *(float4*)&Prow[r * 1024 + t * 4] = g[r];
  }
}

// ---------------------------------------------------------------------------
extern "C" void kernel_launch(void* const* d_in, const int* in_sizes, int n_in,
                              void* d_out, int out_size, void* d_ws,
                              size_t ws_size, hipStream_t stream) {
  const float* x = (const float*)d_in[0];
  const float* Wq = (const float*)d_in[1];
  const float* Wk = (const float*)d_in[2];
  const float* Wv = (const float*)d_in[3];
  const float* Ws = (const float*)d_in[4];

  float* out = (float*)d_out;
  float* Z = out;                                  // [4096, 512]
  float* P = Z + (size_t)N_TOK * DM;               // [4096, 4096]
  float* S = P + (size_t)N_TOK * N_TOK;            // [4096, 4096]

  float* ws = (float*)d_ws;
  float* Q = ws;                                   // [4096, 512]
  float* Km = Q + (size_t)N_TOK * DM;              // [4096, 512]
  float* Vm = Km + (size_t)N_TOK * DM;             // [4096, 512]
  float* sg = Vm + (size_t)N_TOK * DM;             // [4096]

  const dim3 blk(256);
  const dim3 gQKV(DM / 64, N_TOK / 64);            // 8 x 64
  const dim3 gS(N_TOK / 64, N_TOK / 64);           // 64 x 64

  // Q, K, V projections: x @ W^T  (NT gemm)
  gemm_kernel<1><<<gQKV, blk, 0, stream>>>(x, Wq, Q, N_TOK, DM, DM, 1.0f);
  gemm_kernel<1><<<gQKV, blk, 0, stream>>>(x, Wk, Km, N_TOK, DM, DM, 1.0f);
  gemm_kernel<1><<<gQKV, blk, 0, stream>>>(x, Wv, Vm, N_TOK, DM, DM, 1.0f);
  sigma_kernel<<<N_TOK / 4, blk, 0, stream>>>(x, Ws, sg);

  // scores = Q @ K^T / sqrt(D) written straight into the S output slice
  gemm_kernel<1><<<gS, blk, 0, stream>>>(Q, Km, S, N_TOK, N_TOK, DM,
                                         1.0f / sqrtf((float)DM));
  // softmax in place -> S
  softmax_kernel<<<N_TOK, blk, 0, stream>>>(S);
  // Z = S @ V  (NN gemm)
  gemm_kernel<0><<<gQKV, blk, 0, stream>>>(S, Vm, Z, N_TOK, DM, N_TOK, 1.0f);
  // P from sigma
  p_kernel<<<N_TOK, blk, 0, stream>>>(sg, P);
}

// Round 2
// 358.428 us; speedup vs baseline: 2.2973x; 2.2973x over previous
//
#include <hip/hip_runtime.h>
#include <math.h>

#define N_TOK 4096
#define DM 512

typedef __bf16 bf16x8 __attribute__((ext_vector_type(8)));
typedef float f32x4 __attribute__((ext_vector_type(4)));

// ---- bf16 helpers (manual RNE; storage as ushort) --------------------------
__device__ __forceinline__ unsigned short f2bf(float f) {
  unsigned int u = __float_as_uint(f);
  u += 0x7fffu + ((u >> 16) & 1u);
  return (unsigned short)(u >> 16);
}
__device__ __forceinline__ float bf2f(unsigned short h) {
  return __uint_as_float(((unsigned int)h) << 16);
}

__device__ __forceinline__ void async_ld16(const ushort* g, ushort* l) {
  __builtin_amdgcn_global_load_lds(
      (const __attribute__((address_space(1))) void*)g,
      (__attribute__((address_space(3))) void*)l, 16, 0, 0);
}

// ---------------------------------------------------------------------------
// split fp32 -> (hi, lo) bf16 planes.  n multiple of 1024.
// ---------------------------------------------------------------------------
__global__ __launch_bounds__(256) void split_hilo(const float* __restrict__ src,
                                                  ushort* __restrict__ hi,
                                                  ushort* __restrict__ lo) {
  int i = (blockIdx.x * 256 + threadIdx.x) * 4;
  float4 v = *(const float4*)&src[i];
  ushort4 h, l;
  h.x = f2bf(v.x); l.x = f2bf(v.x - bf2f(h.x));
  h.y = f2bf(v.y); l.y = f2bf(v.y - bf2f(h.y));
  h.z = f2bf(v.z); l.z = f2bf(v.z - bf2f(h.z));
  h.w = f2bf(v.w); l.w = f2bf(v.w - bf2f(h.w));
  *(ushort4*)&hi[i] = h;
  *(ushort4*)&lo[i] = l;
}

// ---------------------------------------------------------------------------
// MFMA NT GEMM: C[m,n] = sum_k A[m,k]*B[n,k]  (both A,B row-major over K)
// BM=BN=128, BK=32, 256 threads = 4 waves (2x2 of 64x64), 16x16x32 bf16 MFMA.
// SPLIT=1: A=(Ahi+Alo), B=(Bhi+Blo); acc = hh + hl + lh  (fp32-faithful).
// EPI=0: Cf[m*ldc+n] = acc*scale.
// EPI=1 (QKV, N=1536): n<512 -> Qhi/Qlo bf16; n<1024 -> Khi/Klo; else Vf fp32.
// ---------------------------------------------------------------------------
template <int SPLIT, int EPI>
__global__ __launch_bounds__(256) void mfma_gemm(
    const ushort* __restrict__ Ahi, const ushort* __restrict__ Alo, int lda,
    const ushort* __restrict__ Bhi, const ushort* __restrict__ Blo, int ldb,
    int K, float scale, float* __restrict__ Cf, int ldc,
    ushort* __restrict__ Qhi, ushort* __restrict__ Qlo,
    ushort* __restrict__ Khi, ushort* __restrict__ Klo) {
  __shared__ ushort lds[(SPLIT ? 4 : 2) * 128 * 32];
  ushort* Ah = lds;
  ushort* Bh = lds + 128 * 32;
  ushort* Al = SPLIT ? (lds + 2 * 128 * 32) : lds;
  ushort* Bl = SPLIT ? (lds + 3 * 128 * 32) : lds;

  const int t = threadIdx.x;
  const int w = t >> 6, L = t & 63;
  const int wm = (w >> 1) * 64, wn = (w & 1) * 64;
  const int row = L & 15, quad = L >> 4;
  const int bm = blockIdx.y * 128, bn = blockIdx.x * 128;

  f32x4 acc[4][4] = {{}};

  // staging: 512 x 16B chunks per plane; thread t does chunks t and t+256.
  const int c0 = t, c1 = t + 256;
  const int r0 = c0 >> 2, o0 = (c0 & 3) * 8;
  const int r1 = r0 + 64;

  const ushort* ga0 = Ahi + (size_t)(bm + r0) * lda + o0;
  const ushort* ga1 = Ahi + (size_t)(bm + r1) * lda + o0;
  const ushort* gb0 = Bhi + (size_t)(bn + r0) * ldb + o0;
  const ushort* gb1 = Bhi + (size_t)(bn + r1) * ldb + o0;
  const ushort* gal0 = Alo + (size_t)(bm + r0) * lda + o0;
  const ushort* gal1 = Alo + (size_t)(bm + r1) * lda + o0;
  const ushort* gbl0 = Blo + (size_t)(bn + r0) * ldb + o0;
  const ushort* gbl1 = Blo + (size_t)(bn + r1) * ldb + o0;

  for (int k0 = 0; k0 < K; k0 += 32) {
    async_ld16(ga0, Ah + c0 * 8);
    async_ld16(ga1, Ah + c1 * 8);
    async_ld16(gb0, Bh + c0 * 8);
    async_ld16(gb1, Bh + c1 * 8);
    if (SPLIT) {
      async_ld16(gal0, Al + c0 * 8);
      async_ld16(gal1, Al + c1 * 8);
      async_ld16(gbl0, Bl + c0 * 8);
      async_ld16(gbl1, Bl + c1 * 8);
    }
    ga0 += 32; ga1 += 32; gb0 += 32; gb1 += 32;
    if (SPLIT) { gal0 += 32; gal1 += 32; gbl0 += 32; gbl1 += 32; }
    __syncthreads();

    bf16x8 a0[4], b0[4];
#pragma unroll
    for (int i = 0; i < 4; ++i)
      a0[i] = *(const bf16x8*)&Ah[(wm + i * 16 + row) * 32 + quad * 8];
#pragma unroll
    for (int j = 0; j < 4; ++j)
      b0[j] = *(const bf16x8*)&Bh[(wn + j * 16 + row) * 32 + quad * 8];
#pragma unroll
    for (int i = 0; i < 4; ++i)
#pragma unroll
      for (int j = 0; j < 4; ++j)
        acc[i][j] = __builtin_amdgcn_mfma_f32_16x16x32_bf16(a0[i], b0[j],
                                                            acc[i][j], 0, 0, 0);
    if (SPLIT) {
      bf16x8 a1[4], b1[4];
#pragma unroll
      for (int i = 0; i < 4; ++i)
        a1[i] = *(const bf16x8*)&Al[(wm + i * 16 + row) * 32 + quad * 8];
#pragma unroll
      for (int j = 0; j < 4; ++j)
        b1[j] = *(const bf16x8*)&Bl[(wn + j * 16 + row) * 32 + quad * 8];
#pragma unroll
      for (int i = 0; i < 4; ++i)
#pragma unroll
        for (int j = 0; j < 4; ++j)
          acc[i][j] = __builtin_amdgcn_mfma_f32_16x16x32_bf16(
              a0[i], b1[j], acc[i][j], 0, 0, 0);
#pragma unroll
      for (int i = 0; i < 4; ++i)
#pragma unroll
        for (int j = 0; j < 4; ++j)
          acc[i][j] = __builtin_amdgcn_mfma_f32_16x16x32_bf16(
              a1[i], b0[j], acc[i][j], 0, 0, 0);
    }
    __syncthreads();
  }

  // epilogue: C/D layout col = lane&15, row = quad*4 + reg
  if (EPI == 0) {
#pragma unroll
    for (int i = 0; i < 4; ++i)
#pragma unroll
      for (int j = 0; j < 4; ++j)
#pragma unroll
        for (int r = 0; r < 4; ++r) {
          int gr = bm + wm + i * 16 + quad * 4 + r;
          int gc = bn + wn + j * 16 + row;
          Cf[(size_t)gr * ldc + gc] = acc[i][j][r] * scale;
        }
  } else {
    const int region = bn >> 9;  // uniform per block (BN=128 | 512)
#pragma unroll
    for (int i = 0; i < 4; ++i)
#pragma unroll
      for (int j = 0; j < 4; ++j)
#pragma unroll
        for (int r = 0; r < 4; ++r) {
          int gr = bm + wm + i * 16 + quad * 4 + r;
          int nn = (bn & 511) + wn + j * 16 + row;
          float v = acc[i][j][r];
          if (region == 2) {
            Cf[(size_t)gr * 512 + nn] = v;
          } else {
            unsigned short h = f2bf(v);
            unsigned short l = f2bf(v - bf2f(h));
            ushort* H = region ? Khi : Qhi;
            ushort* Lo = region ? Klo : Qlo;
            H[(size_t)gr * 512 + nn] = h;
            Lo[(size_t)gr * 512 + nn] = l;
          }
        }
  }
}

// ---------------------------------------------------------------------------
// Vf [4096x512] fp32 -> VT bf16 [512][4096]
// ---------------------------------------------------------------------------
__global__ __launch_bounds__(256) void transpose_v(const float* __restrict__ Vf,
                                                   ushort* __restrict__ VT) {
  __shared__ float T[32][33];
  const int t = threadIdx.x;
  const int r = t >> 3, c4 = (t & 7) * 4;
  float4 v = *(const float4*)&Vf[(size_t)(blockIdx.y * 32 + r) * 512 +
                                 blockIdx.x * 32 + c4];
  T[r][c4] = v.x; T[r][c4 + 1] = v.y; T[r][c4 + 2] = v.z; T[r][c4 + 3] = v.w;
  __syncthreads();
  ushort4 o;
  o.x = f2bf(T[c4][r]);
  o.y = f2bf(T[c4 + 1][r]);
  o.z = f2bf(T[c4 + 2][r]);
  o.w = f2bf(T[c4 + 3][r]);
  *(ushort4*)&VT[(size_t)(blockIdx.x * 32 + r) * 4096 + blockIdx.y * 32 + c4] = o;
}

// ---------------------------------------------------------------------------
// sigma[i] = clip(dot(x[i,:], Ws), 0.001, 1.0). One wave per row.
// ---------------------------------------------------------------------------
__global__ __launch_bounds__(256) void sigma_kernel(const float* __restrict__ x,
                                                    const float* __restrict__ Ws,
                                                    float* __restrict__ sigma) {
  const int wave = threadIdx.x >> 6;
  const int lane = threadIdx.x & 63;
  const int row = blockIdx.x * 4 + wave;
  const float4* xr = (const float4*)(x + (size_t)row * DM);
  const float4* w = (const float4*)Ws;
  float s = 0.f;
#pragma unroll
  for (int r = 0; r < 2; ++r) {
    float4 a = xr[lane + 64 * r];
    float4 b = w[lane + 64 * r];
    s += a.x * b.x + a.y * b.y + a.z * b.z + a.w * b.w;
  }
#pragma unroll
  for (int off = 32; off > 0; off >>= 1) s += __shfl_down(s, off);
  if (lane == 0) sigma[row] = fminf(fmaxf(s, 0.001f), 1.0f);
}

// ---------------------------------------------------------------------------
// In-place row softmax on fp32 S; also emits bf16 copy S16.
// ---------------------------------------------------------------------------
__global__ __launch_bounds__(256) void softmax_kernel(float* __restrict__ S,
                                                      ushort* __restrict__ S16) {
  __shared__ float red[256];
  const int t = threadIdx.x;
  float* Srow = S + (size_t)blockIdx.x * N_TOK;
  ushort* S16row = S16 + (size_t)blockIdx.x * N_TOK;
  float4 v[4];
  float m = -INFINITY;
#pragma unroll
  for (int r = 0; r < 4; ++r) {
    v[r] = *(float4*)&Srow[r * 1024 + t * 4];
    m = fmaxf(m, fmaxf(fmaxf(v[r].x, v[r].y), fmaxf(v[r].z, v[r].w)));
  }
  red[t] = m;
  __syncthreads();
  for (int off = 128; off > 0; off >>= 1) {
    if (t < off) red[t] = fmaxf(red[t], red[t + off]);
    __syncthreads();
  }
  m = red[0];
  __syncthreads();
  float sum = 0.f;
#pragma unroll
  for (int r = 0; r < 4; ++r) {
    v[r].x = __expf(v[r].x - m);
    v[r].y = __expf(v[r].y - m);
    v[r].z = __expf(v[r].z - m);
    v[r].w = __expf(v[r].w - m);
    sum += v[r].x + v[r].y + v[r].z + v[r].w;
  }
  red[t] = sum;
  __syncthreads();
  for (int off = 128; off > 0; off >>= 1) {
    if (t < off) red[t] += red[t + off];
    __syncthreads();
  }
  const float inv = 1.0f / red[0];
#pragma unroll
  for (int r = 0; r < 4; ++r) {
    v[r].x *= inv; v[r].y *= inv; v[r].z *= inv; v[r].w *= inv;
    *(float4*)&Srow[r * 1024 + t * 4] = v[r];
    ushort4 o;
    o.x = f2bf(v[r].x); o.y = f2bf(v[r].y);
    o.z = f2bf(v[r].z); o.w = f2bf(v[r].w);
    *(ushort4*)&S16row[r * 1024 + t * 4] = o;
  }
}

// ---------------------------------------------------------------------------
// P[i,j] = g / (sum_j g + 1e-8),  g = exp(-0.5*((i-j)/sig)^2) / sqrt(2*pi*sig)
// ---------------------------------------------------------------------------
__global__ __launch_bounds__(256) void p_kernel(const float* __restrict__ sigma,
                                                float* __restrict__ P) {
  __shared__ float red[256];
  const int i = blockIdx.x;
  const int t = threadIdx.x;
  const float sg = sigma[i];
  const float inv2 = -0.5f / (sg * sg);
  const float c = rsqrtf(6.283185307179586f * sg);
  float4 g[4];
  float sum = 0.f;
#pragma unroll
  for (int r = 0; r < 4; ++r) {
    int j = r * 1024 + t * 4;
    float d0 = (float)(i - j);
    float d1 = (float)(i - j - 1);
    float d2 = (float)(i - j - 2);
    float d3 = (float)(i - j - 3);
    g[r].x = __expf(inv2 * d0 * d0) * c;
    g[r].y = __expf(inv2 * d1 * d1) * c;
    g[r].z = __expf(inv2 * d2 * d2) * c;
    g[r].w = __expf(inv2 * d3 * d3) * c;
    sum += g[r].x + g[r].y + g[r].z + g[r].w;
  }
  red[t] = sum;
  __syncthreads();
  for (int off = 128; off > 0; off >>= 1) {
    if (t < off) red[t] += red[t + off];
    __syncthreads();
  }
  const float inv = 1.0f / (red[0] + 1e-8f);
  float* Prow = P + (size_t)i * N_TOK;
#pragma unroll
  for (int r = 0; r < 4; ++r) {
    g[r].x *= inv; g[r].y *= inv; g[r].z *= inv; g[r].w *= inv;
    *(float4*)&Prow[r * 1024 + t * 4] = g[r];
  }
}

// ---------------------------------------------------------------------------
extern "C" void kernel_launch(void* const* d_in, const int* in_sizes, int n_in,
                              void* d_out, int out_size, void* d_ws,
                              size_t ws_size, hipStream_t stream) {
  const float* x = (const float*)d_in[0];
  const float* Wq = (const float*)d_in[1];
  const float* Wk = (const float*)d_in[2];
  const float* Wv = (const float*)d_in[3];
  const float* Ws = (const float*)d_in[4];

  float* out = (float*)d_out;
  float* Z = out;                        // [4096, 512]   fp32
  float* Pout = Z + (size_t)N_TOK * DM;  // [4096, 4096]  fp32 (written LAST)
  float* S = Pout + (size_t)N_TOK * N_TOK;

  // Stage intermediates inside the P slice of d_out (free until p_kernel):
  const size_t E = (size_t)N_TOK * DM;  // 2M elements
  ushort* Qhi = (ushort*)Pout;          // 4MB
  ushort* Qlo = Qhi + E;                // 4MB
  ushort* Khi = Qlo + E;                // 4MB
  ushort* Klo = Khi + E;                // 4MB
  float* Vf = (float*)(Klo + E);        // 8MB
  ushort* VT16 = (ushort*)(Vf + E);     // 4MB
  ushort* S16 = VT16 + E;               // 32MB  (total 60MB <= 64MB)

  // ws: x hi/lo + Wcat hi/lo + sigma  (~11 MB)
  ushort* xhi = (ushort*)d_ws;
  ushort* xlo = xhi + E;
  ushort* Wch = xlo + E;            // [1536 x 512]
  ushort* Wcl = Wch + 3 * DM * DM;
  float* sg = (float*)(Wcl + 3 * DM * DM);

  const dim3 blk(256);

  // 1. pack inputs to hi/lo bf16 planes
  split_hilo<<<E / 1024, blk, 0, stream>>>(x, xhi, xlo);
  split_hilo<<<DM * DM / 1024, blk, 0, stream>>>(Wq, Wch, Wcl);
  split_hilo<<<DM * DM / 1024, blk, 0, stream>>>(Wk, Wch + DM * DM, Wcl + DM * DM);
  split_hilo<<<DM * DM / 1024, blk, 0, stream>>>(Wv, Wch + 2 * DM * DM, Wcl + 2 * DM * DM);
  sigma_kernel<<<N_TOK / 4, blk, 0, stream>>>(x, Ws, sg);

  // 2. fused QKV projection (split-precision): C[4096x1536] = x @ Wcat^T
  mfma_gemm<1, 1><<<dim3(12, 32), blk, 0, stream>>>(
      xhi, xlo, DM, Wch, Wcl, DM, DM, 1.0f, Vf, 0, Qhi, Qlo, Khi, Klo);

  // 3. V -> V^T bf16
  transpose_v<<<dim3(16, 128), blk, 0, stream>>>(Vf, VT16);

  // 4. scores = Q @ K^T / sqrt(D)  (split-precision) -> fp32 S slice
  mfma_gemm<1, 0><<<dim3(32, 32), blk, 0, stream>>>(
      Qhi, Qlo, DM, Khi, Klo, DM, DM, 1.0f / sqrtf((float)DM), S, N_TOK,
      nullptr, nullptr, nullptr, nullptr);

  // 5. softmax in place (+ bf16 copy)
  softmax_kernel<<<N_TOK, blk, 0, stream>>>(S, S16);

  // 6. Z = S @ V   (plain bf16: A=S16, B=V^T)
  mfma_gemm<0, 0><<<dim3(4, 32), blk, 0, stream>>>(
      S16, S16, N_TOK, VT16, VT16, N_TOK, N_TOK, 1.0f, Z, DM,
      nullptr, nullptr, nullptr, nullptr);

  // 7. P from sigma (overwrites the staging region)
  p_kernel<<<N_TOK, blk, 0, stream>>>(sg, Pout);
}

// Round 3
// 280.292 us; speedup vs baseline: 2.9377x; 1.2788x over previous
//
#include <hip/hip_runtime.h>
#include <math.h>

#define N_TOK 4096
#define DM 512

typedef _Float16 f16x8 __attribute__((ext_vector_type(8)));
typedef _Float16 f16x4 __attribute__((ext_vector_type(4)));
typedef float f32x4 __attribute__((ext_vector_type(4)));

__device__ __forceinline__ void async_ld16(const ushort* g, ushort* l) {
  __builtin_amdgcn_global_load_lds(
      (const __attribute__((address_space(1))) void*)g,
      (__attribute__((address_space(3))) void*)l, 16, 0, 0);
}

// ---------------------------------------------------------------------------
// fp32 -> fp16 pack. n multiple of 1024.
// ---------------------------------------------------------------------------
__global__ __launch_bounds__(256) void pack16(const float* __restrict__ src,
                                              _Float16* __restrict__ dst) {
  int i = (blockIdx.x * 256 + threadIdx.x) * 4;
  float4 v = *(const float4*)&src[i];
  f16x4 o;
  o.x = (_Float16)v.x; o.y = (_Float16)v.y;
  o.z = (_Float16)v.z; o.w = (_Float16)v.w;
  *(f16x4*)&dst[i] = o;
}

// ---------------------------------------------------------------------------
// fp16 MFMA NT GEMM: C[m,n] = scale * sum_k A[m,k]*B[n,k]
// BM=BN=128, BK=32, 256 thr = 4 waves (2x2 of 64x64), 16x16x32 f16 MFMA.
// K = per-chunk length; k-base = blockIdx.z * K (split-K).
// EPI=0: Cf[m*ldc+n] = acc*scale
// EPI=1: QKV fused (N=1536): bn<512 -> Q16 fp16; <1024 -> K16 fp16; else Vf f32
// EPI=2: split-K S@V: z==0 -> Cf; z==1,2 -> PartA+(z-1)*2M; z==3 -> PartB
// ---------------------------------------------------------------------------
template <int EPI>
__global__ __launch_bounds__(256) void mfma_f16(
    const _Float16* __restrict__ A, int lda, const _Float16* __restrict__ B,
    int ldb, int K, float scale, float* __restrict__ Cf, int ldc,
    _Float16* __restrict__ Q16, _Float16* __restrict__ K16,
    float* __restrict__ Vf, float* __restrict__ PartA,
    float* __restrict__ PartB) {
  __shared__ _Float16 lds[2 * 128 * 32];
  _Float16* Ah = lds;
  _Float16* Bh = lds + 128 * 32;

  const int t = threadIdx.x;
  const int w = t >> 6, L = t & 63;
  const int wm = (w >> 1) * 64, wn = (w & 1) * 64;
  const int row = L & 15, quad = L >> 4;
  const int bm = blockIdx.y * 128, bn = blockIdx.x * 128;
  const int kbase = blockIdx.z * K;

  f32x4 acc[4][4] = {{}};

  // staging: 512 x 16B chunks per matrix; thread t does chunks t and t+256.
  const int c0 = t, c1 = t + 256;
  const int r0 = c0 >> 2, o0 = (c0 & 3) * 8;
  const int r1 = r0 + 64;

  const ushort* ga0 = (const ushort*)(A + (size_t)(bm + r0) * lda + kbase + o0);
  const ushort* ga1 = (const ushort*)(A + (size_t)(bm + r1) * lda + kbase + o0);
  const ushort* gb0 = (const ushort*)(B + (size_t)(bn + r0) * ldb + kbase + o0);
  const ushort* gb1 = (const ushort*)(B + (size_t)(bn + r1) * ldb + kbase + o0);

  for (int k0 = 0; k0 < K; k0 += 32) {
    async_ld16(ga0, (ushort*)(Ah + c0 * 8));
    async_ld16(ga1, (ushort*)(Ah + c1 * 8));
    async_ld16(gb0, (ushort*)(Bh + c0 * 8));
    async_ld16(gb1, (ushort*)(Bh + c1 * 8));
    ga0 += 32; ga1 += 32; gb0 += 32; gb1 += 32;
    __syncthreads();

    f16x8 a0[4], b0[4];
#pragma unroll
    for (int i = 0; i < 4; ++i)
      a0[i] = *(const f16x8*)&Ah[(wm + i * 16 + row) * 32 + quad * 8];
#pragma unroll
    for (int j = 0; j < 4; ++j)
      b0[j] = *(const f16x8*)&Bh[(wn + j * 16 + row) * 32 + quad * 8];
#pragma unroll
    for (int i = 0; i < 4; ++i)
#pragma unroll
      for (int j = 0; j < 4; ++j)
        acc[i][j] = __builtin_amdgcn_mfma_f32_16x16x32_f16(a0[i], b0[j],
                                                           acc[i][j], 0, 0, 0);
    __syncthreads();
  }

  // epilogue: C/D layout col = lane&15, row = quad*4 + reg
  if (EPI == 0) {
#pragma unroll
    for (int i = 0; i < 4; ++i)
#pragma unroll
      for (int j = 0; j < 4; ++j)
#pragma unroll
        for (int r = 0; r < 4; ++r) {
          int gr = bm + wm + i * 16 + quad * 4 + r;
          int gc = bn + wn + j * 16 + row;
          Cf[(size_t)gr * ldc + gc] = acc[i][j][r] * scale;
        }
  } else if (EPI == 1) {
    const int region = bn >> 9;  // uniform per block
#pragma unroll
    for (int i = 0; i < 4; ++i)
#pragma unroll
      for (int j = 0; j < 4; ++j)
#pragma unroll
        for (int r = 0; r < 4; ++r) {
          int gr = bm + wm + i * 16 + quad * 4 + r;
          int nn = (bn & 511) + wn + j * 16 + row;
          float v = acc[i][j][r];
          if (region == 2) {
            Vf[(size_t)gr * 512 + nn] = v;
          } else {
            _Float16* D = region ? K16 : Q16;
            D[(size_t)gr * 512 + nn] = (_Float16)v;
          }
        }
  } else {
    const int z = blockIdx.z;
    float* dst = (z == 0) ? Cf
                          : ((z < 3) ? PartA + (size_t)(z - 1) * 2097152
                                     : PartB);
#pragma unroll
    for (int i = 0; i < 4; ++i)
#pragma unroll
      for (int j = 0; j < 4; ++j)
#pragma unroll
        for (int r = 0; r < 4; ++r) {
          int gr = bm + wm + i * 16 + quad * 4 + r;
          int gc = bn + wn + j * 16 + row;
          dst[(size_t)gr * ldc + gc] = acc[i][j][r] * scale;
        }
  }
}

// ---------------------------------------------------------------------------
// Z += PartA[0] + PartA[1] + PartB   (split-K reduction)
// ---------------------------------------------------------------------------
__global__ __launch_bounds__(256) void reduce_z(float* __restrict__ Z,
                                                const float* __restrict__ PartA,
                                                const float* __restrict__ PartB) {
  int i = (blockIdx.x * 256 + threadIdx.x) * 4;
  float4 z = *(const float4*)&Z[i];
  float4 a = *(const float4*)&PartA[i];
  float4 b = *(const float4*)&PartA[2097152 + i];
  float4 c = *(const float4*)&PartB[i];
  z.x += a.x + b.x + c.x;
  z.y += a.y + b.y + c.y;
  z.z += a.z + b.z + c.z;
  z.w += a.w + b.w + c.w;
  *(float4*)&Z[i] = z;
}

// ---------------------------------------------------------------------------
// Vf [4096x512] fp32 -> VT fp16 [512][4096]
// ---------------------------------------------------------------------------
__global__ __launch_bounds__(256) void transpose_v(const float* __restrict__ Vf,
                                                   _Float16* __restrict__ VT) {
  __shared__ float T[32][33];
  const int t = threadIdx.x;
  const int r = t >> 3, c4 = (t & 7) * 4;
  float4 v = *(const float4*)&Vf[(size_t)(blockIdx.y * 32 + r) * 512 +
                                 blockIdx.x * 32 + c4];
  T[r][c4] = v.x; T[r][c4 + 1] = v.y; T[r][c4 + 2] = v.z; T[r][c4 + 3] = v.w;
  __syncthreads();
  f16x4 o;
  o.x = (_Float16)T[c4][r];
  o.y = (_Float16)T[c4 + 1][r];
  o.z = (_Float16)T[c4 + 2][r];
  o.w = (_Float16)T[c4 + 3][r];
  *(f16x4*)&VT[(size_t)(blockIdx.x * 32 + r) * 4096 + blockIdx.y * 32 + c4] = o;
}

// ---------------------------------------------------------------------------
// sigma[i] = clip(dot(x[i,:], Ws), 0.001, 1.0). One wave per row.
// ---------------------------------------------------------------------------
__global__ __launch_bounds__(256) void sigma_kernel(const float* __restrict__ x,
                                                    const float* __restrict__ Ws,
                                                    float* __restrict__ sigma) {
  const int wave = threadIdx.x >> 6;
  const int lane = threadIdx.x & 63;
  const int row = blockIdx.x * 4 + wave;
  const float4* xr = (const float4*)(x + (size_t)row * DM);
  const float4* w = (const float4*)Ws;
  float s = 0.f;
#pragma unroll
  for (int r = 0; r < 2; ++r) {
    float4 a = xr[lane + 64 * r];
    float4 b = w[lane + 64 * r];
    s += a.x * b.x + a.y * b.y + a.z * b.z + a.w * b.w;
  }
#pragma unroll
  for (int off = 32; off > 0; off >>= 1) s += __shfl_down(s, off);
  if (lane == 0) sigma[row] = fminf(fmaxf(s, 0.001f), 1.0f);
}

// ---------------------------------------------------------------------------
// In-place row softmax on fp32 S; also emits fp16 copy S16.
// ---------------------------------------------------------------------------
__global__ __launch_bounds__(256) void softmax_kernel(float* __restrict__ S,
                                                      _Float16* __restrict__ S16) {
  __shared__ float red[256];
  const int t = threadIdx.x;
  float* Srow = S + (size_t)blockIdx.x * N_TOK;
  _Float16* S16row = S16 + (size_t)blockIdx.x * N_TOK;
  float4 v[4];
  float m = -INFINITY;
#pragma unroll
  for (int r = 0; r < 4; ++r) {
    v[r] = *(float4*)&Srow[r * 1024 + t * 4];
    m = fmaxf(m, fmaxf(fmaxf(v[r].x, v[r].y), fmaxf(v[r].z, v[r].w)));
  }
  red[t] = m;
  __syncthreads();
  for (int off = 128; off > 0; off >>= 1) {
    if (t < off) red[t] = fmaxf(red[t], red[t + off]);
    __syncthreads();
  }
  m = red[0];
  __syncthreads();
  float sum = 0.f;
#pragma unroll
  for (int r = 0; r < 4; ++r) {
    v[r].x = __expf(v[r].x - m);
    v[r].y = __expf(v[r].y - m);
    v[r].z = __expf(v[r].z - m);
    v[r].w = __expf(v[r].w - m);
    sum += v[r].x + v[r].y + v[r].z + v[r].w;
  }
  red[t] = sum;
  __syncthreads();
  for (int off = 128; off > 0; off >>= 1) {
    if (t < off) red[t] += red[t + off];
    __syncthreads();
  }
  const float inv = 1.0f / red[0];
#pragma unroll
  for (int r = 0; r < 4; ++r) {
    v[r].x *= inv; v[r].y *= inv; v[r].z *= inv; v[r].w *= inv;
    *(float4*)&Srow[r * 1024 + t * 4] = v[r];
    f16x4 o;
    o.x = (_Float16)v[r].x; o.y = (_Float16)v[r].y;
    o.z = (_Float16)v[r].z; o.w = (_Float16)v[r].w;
    *(f16x4*)&S16row[r * 1024 + t * 4] = o;
  }
}

// ---------------------------------------------------------------------------
// P[i,j] = g / (sum_j g + 1e-8),  g = exp(-0.5*((i-j)/sig)^2) / sqrt(2*pi*sig)
// ---------------------------------------------------------------------------
__global__ __launch_bounds__(256) void p_kernel(const float* __restrict__ sigma,
                                                float* __restrict__ P) {
  __shared__ float red[256];
  const int i = blockIdx.x;
  const int t = threadIdx.x;
  const float sg = sigma[i];
  const float inv2 = -0.5f / (sg * sg);
  const float c = rsqrtf(6.283185307179586f * sg);
  float4 g[4];
  float sum = 0.f;
#pragma unroll
  for (int r = 0; r < 4; ++r) {
    int j = r * 1024 + t * 4;
    float d0 = (float)(i - j);
    float d1 = (float)(i - j - 1);
    float d2 = (float)(i - j - 2);
    float d3 = (float)(i - j - 3);
    g[r].x = __expf(inv2 * d0 * d0) * c;
    g[r].y = __expf(inv2 * d1 * d1) * c;
    g[r].z = __expf(inv2 * d2 * d2) * c;
    g[r].w = __expf(inv2 * d3 * d3) * c;
    sum += g[r].x + g[r].y + g[r].z + g[r].w;
  }
  red[t] = sum;
  __syncthreads();
  for (int off = 128; off > 0; off >>= 1) {
    if (t < off) red[t] += red[t + off];
    __syncthreads();
  }
  const float inv = 1.0f / (red[0] + 1e-8f);
  float* Prow = P + (size_t)i * N_TOK;
#pragma unroll
  for (int r = 0; r < 4; ++r) {
    g[r].x *= inv; g[r].y *= inv; g[r].z *= inv; g[r].w *= inv;
    *(float4*)&Prow[r * 1024 + t * 4] = g[r];
  }
}

// ---------------------------------------------------------------------------
extern "C" void kernel_launch(void* const* d_in, const int* in_sizes, int n_in,
                              void* d_out, int out_size, void* d_ws,
                              size_t ws_size, hipStream_t stream) {
  const float* x = (const float*)d_in[0];
  const float* Wq = (const float*)d_in[1];
  const float* Wk = (const float*)d_in[2];
  const float* Wv = (const float*)d_in[3];
  const float* Ws = (const float*)d_in[4];

  float* out = (float*)d_out;
  float* Z = out;                        // [4096, 512]   fp32
  float* Pout = Z + (size_t)N_TOK * DM;  // [4096, 4096]  fp32 (written LAST)
  float* S = Pout + (size_t)N_TOK * N_TOK;

  // Stage intermediates inside the P slice of d_out (free until p_kernel):
  const size_t E = (size_t)N_TOK * DM;     // 2M elements
  _Float16* Q16 = (_Float16*)Pout;         // [ 0, 4) MB
  _Float16* K16 = Q16 + E;                 // [ 4, 8) MB
  float* Vf = (float*)(K16 + E);           // [ 8,16) MB
  _Float16* VT16 = (_Float16*)(Vf + E);    // [16,20) MB
  _Float16* S16 = VT16 + E;                // [20,52) MB
  // split-K partials reuse dead regions at S@V time:
  float* PartA = (float*)Pout;             // [ 0,16) MB (Q16/K16/Vf dead)
  float* PartB = (float*)(S16 + (size_t)N_TOK * N_TOK);  // [52,60) MB slack

  // ws: x16 (4MB) + Wcat16 (1.5MB) + sigma
  _Float16* x16 = (_Float16*)d_ws;
  _Float16* Wc16 = x16 + E;                // [1536 x 512]
  float* sg = (float*)(Wc16 + 3 * DM * DM);

  const dim3 blk(256);

  // 1. pack inputs to fp16
  pack16<<<E / 1024, blk, 0, stream>>>(x, x16);
  pack16<<<DM * DM / 1024, blk, 0, stream>>>(Wq, Wc16);
  pack16<<<DM * DM / 1024, blk, 0, stream>>>(Wk, Wc16 + DM * DM);
  pack16<<<DM * DM / 1024, blk, 0, stream>>>(Wv, Wc16 + 2 * DM * DM);
  sigma_kernel<<<N_TOK / 4, blk, 0, stream>>>(x, Ws, sg);

  // 2. fused QKV projection: [4096x1536] = x16 @ Wcat^T
  mfma_f16<1><<<dim3(12, 32), blk, 0, stream>>>(
      x16, DM, Wc16, DM, DM, 1.0f, nullptr, 0, Q16, K16, Vf, nullptr, nullptr);

  // 3. V -> V^T fp16
  transpose_v<<<dim3(16, 128), blk, 0, stream>>>(Vf, VT16);

  // 4. scores = Q @ K^T / sqrt(D) -> fp32 S slice
  mfma_f16<0><<<dim3(32, 32), blk, 0, stream>>>(
      Q16, DM, K16, DM, DM, 1.0f / sqrtf((float)DM), S, N_TOK, nullptr,
      nullptr, nullptr, nullptr, nullptr);

  // 5. softmax in place (+ fp16 copy)
  softmax_kernel<<<N_TOK, blk, 0, stream>>>(S, S16);

  // 6. Z = S @ V, split-K x4 (z=0 -> Z, z=1..3 -> partials)
  mfma_f16<2><<<dim3(4, 32, 4), blk, 0, stream>>>(
      S16, N_TOK, VT16, N_TOK, N_TOK / 4, 1.0f, Z, DM, nullptr, nullptr,
      nullptr, PartA, PartB);
  reduce_z<<<E / 1024, blk, 0, stream>>>(Z, PartA, PartB);

  // 7. P from sigma (overwrites the staging region)
  p_kernel<<<N_TOK, blk, 0, stream>>>(sg, Pout);
}

// Round 4
// 261.989 us; speedup vs baseline: 3.1430x; 1.0699x over previous
//
#include <hip/hip_runtime.h>
#include <math.h>

#define N_TOK 4096
#define DM 512

typedef _Float16 f16x8 __attribute__((ext_vector_type(8)));
typedef _Float16 f16x4 __attribute__((ext_vector_type(4)));
typedef float f32x4 __attribute__((ext_vector_type(4)));

__device__ __forceinline__ void async_ld16(const ushort* g, ushort* l) {
  __builtin_amdgcn_global_load_lds(
      (const __attribute__((address_space(1))) void*)g,
      (__attribute__((address_space(3))) void*)l, 16, 0, 0);
}

// ---------------------------------------------------------------------------
// Fused pack + sigma.
// blocks [0,2048): pack x (1024 elems = rows 2b,2b+1) and compute sigma rows
// blocks [2048,2816): pack Wq|Wk|Wv into concatenated Wc16
// ---------------------------------------------------------------------------
__global__ __launch_bounds__(256) void pack_sigma(
    const float* __restrict__ x, const float* __restrict__ Wq,
    const float* __restrict__ Wk, const float* __restrict__ Wv,
    const float* __restrict__ Ws, _Float16* __restrict__ x16,
    _Float16* __restrict__ Wc16, float* __restrict__ sg) {
  const int b = blockIdx.x;
  const int t = threadIdx.x;
  if (b < 2048) {
    int i = b * 1024 + t * 4;
    float4 v = *(const float4*)&x[i];
    f16x4 o;
    o.x = (_Float16)v.x; o.y = (_Float16)v.y;
    o.z = (_Float16)v.z; o.w = (_Float16)v.w;
    *(f16x4*)&x16[i] = o;
    // sigma: threads [0,128) -> row 2b, [128,256) -> row 2b+1
    int col = (t * 4) & 511;
    float4 w = *(const float4*)&Ws[col];
    float p = v.x * w.x + v.y * w.y + v.z * w.z + v.w * w.w;
    __shared__ float red[256];
    red[t] = p;
    __syncthreads();
    int lt = t & 127;
    for (int off = 64; off > 0; off >>= 1) {
      if (lt < off) red[t] += red[t + off];
      __syncthreads();
    }
    if (lt == 0) {
      float s = red[t];
      sg[2 * b + (t >> 7)] = fminf(fmaxf(s, 0.001f), 1.0f);
    }
  } else {
    int e = (b - 2048) * 1024 + t * 4;
    const float* src;
    int le = e & (DM * DM - 1);
    if (e < DM * DM) src = Wq + le;
    else if (e < 2 * DM * DM) src = Wk + le;
    else src = Wv + le;
    float4 v = *(const float4*)src;
    f16x4 o;
    o.x = (_Float16)v.x; o.y = (_Float16)v.y;
    o.z = (_Float16)v.z; o.w = (_Float16)v.w;
    *(f16x4*)&Wc16[e] = o;
  }
}

// ---------------------------------------------------------------------------
// fp16 MFMA NT GEMM: C[m,n] = scale * sum_k A[m,k]*B[n,k]
// BM=BN=128, BK=32, 256 thr = 4 waves (2x2 of 64x64), 16x16x32 f16 MFMA.
// EPI=1: QKV fused (N=1536): region bn>>9 -> D0(Q16)/D1(K16)/D2(V16), fp16
// EPI=3: fp16 out: D0[gr*ldc+gc] = (f16)(acc*scale)        (raw scores)
// EPI=2: split-K S@V: z==0 -> Cf (fp32, ldc); z>0 -> Part+(z-1)*2M
// ---------------------------------------------------------------------------
template <int EPI>
__global__ __launch_bounds__(256) void mfma_f16(
    const _Float16* __restrict__ A, int lda, const _Float16* __restrict__ B,
    int ldb, int K, float scale, float* __restrict__ Cf, int ldc,
    _Float16* __restrict__ D0, _Float16* __restrict__ D1,
    _Float16* __restrict__ D2, float* __restrict__ Part) {
  __shared__ _Float16 lds[2 * 128 * 32];
  _Float16* Ah = lds;
  _Float16* Bh = lds + 128 * 32;

  const int t = threadIdx.x;
  const int w = t >> 6, L = t & 63;
  const int wm = (w >> 1) * 64, wn = (w & 1) * 64;
  const int row = L & 15, quad = L >> 4;
  const int bm = blockIdx.y * 128, bn = blockIdx.x * 128;
  const int kbase = blockIdx.z * K;

  f32x4 acc[4][4] = {{}};

  const int c0 = t, c1 = t + 256;
  const int r0 = c0 >> 2, o0 = (c0 & 3) * 8;
  const int r1 = r0 + 64;

  const ushort* ga0 = (const ushort*)(A + (size_t)(bm + r0) * lda + kbase + o0);
  const ushort* ga1 = (const ushort*)(A + (size_t)(bm + r1) * lda + kbase + o0);
  const ushort* gb0 = (const ushort*)(B + (size_t)(bn + r0) * ldb + kbase + o0);
  const ushort* gb1 = (const ushort*)(B + (size_t)(bn + r1) * ldb + kbase + o0);

  for (int k0 = 0; k0 < K; k0 += 32) {
    async_ld16(ga0, (ushort*)(Ah + c0 * 8));
    async_ld16(ga1, (ushort*)(Ah + c1 * 8));
    async_ld16(gb0, (ushort*)(Bh + c0 * 8));
    async_ld16(gb1, (ushort*)(Bh + c1 * 8));
    ga0 += 32; ga1 += 32; gb0 += 32; gb1 += 32;
    __syncthreads();

    f16x8 a0[4], b0[4];
#pragma unroll
    for (int i = 0; i < 4; ++i)
      a0[i] = *(const f16x8*)&Ah[(wm + i * 16 + row) * 32 + quad * 8];
#pragma unroll
    for (int j = 0; j < 4; ++j)
      b0[j] = *(const f16x8*)&Bh[(wn + j * 16 + row) * 32 + quad * 8];
#pragma unroll
    for (int i = 0; i < 4; ++i)
#pragma unroll
      for (int j = 0; j < 4; ++j)
        acc[i][j] = __builtin_amdgcn_mfma_f32_16x16x32_f16(a0[i], b0[j],
                                                           acc[i][j], 0, 0, 0);
    __syncthreads();
  }

  // epilogue: C/D layout col = lane&15, row = quad*4 + reg
  if (EPI == 1) {
    const int region = bn >> 9;  // uniform per block
    _Float16* D = (region == 0) ? D0 : ((region == 1) ? D1 : D2);
#pragma unroll
    for (int i = 0; i < 4; ++i)
#pragma unroll
      for (int j = 0; j < 4; ++j)
#pragma unroll
        for (int r = 0; r < 4; ++r) {
          int gr = bm + wm + i * 16 + quad * 4 + r;
          int nn = (bn & 511) + wn + j * 16 + row;
          D[(size_t)gr * 512 + nn] = (_Float16)acc[i][j][r];
        }
  } else if (EPI == 3) {
#pragma unroll
    for (int i = 0; i < 4; ++i)
#pragma unroll
      for (int j = 0; j < 4; ++j)
#pragma unroll
        for (int r = 0; r < 4; ++r) {
          int gr = bm + wm + i * 16 + quad * 4 + r;
          int gc = bn + wn + j * 16 + row;
          D0[(size_t)gr * ldc + gc] = (_Float16)(acc[i][j][r] * scale);
        }
  } else {
    const int z = blockIdx.z;
    float* dst = (z == 0) ? Cf : (Part + (size_t)(z - 1) * 2097152);
#pragma unroll
    for (int i = 0; i < 4; ++i)
#pragma unroll
      for (int j = 0; j < 4; ++j)
#pragma unroll
        for (int r = 0; r < 4; ++r) {
          int gr = bm + wm + i * 16 + quad * 4 + r;
          int gc = bn + wn + j * 16 + row;
          dst[(size_t)gr * ldc + gc] = acc[i][j][r] * scale;
        }
  }
}

// ---------------------------------------------------------------------------
// V16 [4096x512] fp16 -> VT16 [512][4096] fp16
// ---------------------------------------------------------------------------
__global__ __launch_bounds__(256) void transpose16(
    const _Float16* __restrict__ V16, _Float16* __restrict__ VT) {
  __shared__ _Float16 T[32][34];
  const int t = threadIdx.x;
  const int r = t >> 3, c4 = (t & 7) * 4;
  f16x4 v = *(const f16x4*)&V16[(size_t)(blockIdx.y * 32 + r) * 512 +
                                blockIdx.x * 32 + c4];
  T[r][c4] = v.x; T[r][c4 + 1] = v.y; T[r][c4 + 2] = v.z; T[r][c4 + 3] = v.w;
  __syncthreads();
  f16x4 o;
  o.x = T[c4][r]; o.y = T[c4 + 1][r]; o.z = T[c4 + 2][r]; o.w = T[c4 + 3][r];
  *(f16x4*)&VT[(size_t)(blockIdx.x * 32 + r) * 4096 + blockIdx.y * 32 + c4] = o;
}

// ---------------------------------------------------------------------------
// Softmax: read raw fp16 scores Sc (one row/block), fp32 math, write
// S fp32 (output) + softmaxed fp16 back into Sc in place.
// ---------------------------------------------------------------------------
__global__ __launch_bounds__(256) void softmax_kernel(
    _Float16* __restrict__ Sc, float* __restrict__ S) {
  __shared__ float red[256];
  const int t = threadIdx.x;
  _Float16* Srow16 = Sc + (size_t)blockIdx.x * N_TOK;
  float* Srow = S + (size_t)blockIdx.x * N_TOK;
  float f[16];
  float m = -INFINITY;
#pragma unroll
  for (int r = 0; r < 4; ++r) {
    f16x4 h = *(const f16x4*)&Srow16[r * 1024 + t * 4];
    f[r * 4 + 0] = (float)h.x; f[r * 4 + 1] = (float)h.y;
    f[r * 4 + 2] = (float)h.z; f[r * 4 + 3] = (float)h.w;
    m = fmaxf(m, fmaxf(fmaxf(f[r * 4], f[r * 4 + 1]),
                       fmaxf(f[r * 4 + 2], f[r * 4 + 3])));
  }
  red[t] = m;
  __syncthreads();
  for (int off = 128; off > 0; off >>= 1) {
    if (t < off) red[t] = fmaxf(red[t], red[t + off]);
    __syncthreads();
  }
  m = red[0];
  __syncthreads();
  float sum = 0.f;
#pragma unroll
  for (int i = 0; i < 16; ++i) {
    f[i] = __expf(f[i] - m);
    sum += f[i];
  }
  red[t] = sum;
  __syncthreads();
  for (int off = 128; off > 0; off >>= 1) {
    if (t < off) red[t] += red[t + off];
    __syncthreads();
  }
  const float inv = 1.0f / red[0];
#pragma unroll
  for (int r = 0; r < 4; ++r) {
    float4 o;
    o.x = f[r * 4 + 0] * inv; o.y = f[r * 4 + 1] * inv;
    o.z = f[r * 4 + 2] * inv; o.w = f[r * 4 + 3] * inv;
    *(float4*)&Srow[r * 1024 + t * 4] = o;
    f16x4 h;
    h.x = (_Float16)o.x; h.y = (_Float16)o.y;
    h.z = (_Float16)o.z; h.w = (_Float16)o.w;
    *(f16x4*)&Srow16[r * 1024 + t * 4] = h;
  }
}

// ---------------------------------------------------------------------------
// Fused tail: blocks [0,4096) -> P rows; blocks [4096,6144) -> Z += partials
// ---------------------------------------------------------------------------
__global__ __launch_bounds__(256) void tail_kernel(
    const float* __restrict__ sigma, float* __restrict__ P,
    float* __restrict__ Z, const float* __restrict__ Part) {
  const int t = threadIdx.x;
  if (blockIdx.x >= 4096) {
    int i = (blockIdx.x - 4096) * 1024 + t * 4;
    float4 z = *(const float4*)&Z[i];
    float4 a = *(const float4*)&Part[i];
    float4 b = *(const float4*)&Part[2097152 + i];
    float4 c = *(const float4*)&Part[2 * 2097152 + i];
    z.x += a.x + b.x + c.x;
    z.y += a.y + b.y + c.y;
    z.z += a.z + b.z + c.z;
    z.w += a.w + b.w + c.w;
    *(float4*)&Z[i] = z;
    return;
  }
  __shared__ float red[256];
  const int i = blockIdx.x;
  const float sg = sigma[i];
  const float inv2 = -0.5f / (sg * sg);
  const float c = rsqrtf(6.283185307179586f * sg);
  float4 g[4];
  float sum = 0.f;
#pragma unroll
  for (int r = 0; r < 4; ++r) {
    int j = r * 1024 + t * 4;
    float d0 = (float)(i - j);
    float d1 = (float)(i - j - 1);
    float d2 = (float)(i - j - 2);
    float d3 = (float)(i - j - 3);
    g[r].x = __expf(inv2 * d0 * d0) * c;
    g[r].y = __expf(inv2 * d1 * d1) * c;
    g[r].z = __expf(inv2 * d2 * d2) * c;
    g[r].w = __expf(inv2 * d3 * d3) * c;
    sum += g[r].x + g[r].y + g[r].z + g[r].w;
  }
  red[t] = sum;
  __syncthreads();
  for (int off = 128; off > 0; off >>= 1) {
    if (t < off) red[t] += red[t + off];
    __syncthreads();
  }
  const float inv = 1.0f / (red[0] + 1e-8f);
  float* Prow = P + (size_t)i * N_TOK;
#pragma unroll
  for (int r = 0; r < 4; ++r) {
    g[r].x *= inv; g[r].y *= inv; g[r].z *= inv; g[r].w *= inv;
    *(float4*)&Prow[r * 1024 + t * 4] = g[r];
  }
}

// ---------------------------------------------------------------------------
extern "C" void kernel_launch(void* const* d_in, const int* in_sizes, int n_in,
                              void* d_out, int out_size, void* d_ws,
                              size_t ws_size, hipStream_t stream) {
  const float* x = (const float*)d_in[0];
  const float* Wq = (const float*)d_in[1];
  const float* Wk = (const float*)d_in[2];
  const float* Wv = (const float*)d_in[3];
  const float* Ws = (const float*)d_in[4];

  float* out = (float*)d_out;
  float* Z = out;                        // [4096, 512]   fp32
  float* Pout = Z + (size_t)N_TOK * DM;  // [4096, 4096]  fp32 (written LAST)
  float* S = Pout + (size_t)N_TOK * N_TOK;

  // Stage intermediates inside the P slice of d_out (free until tail):
  const size_t E = (size_t)N_TOK * DM;   // 2M elements
  _Float16* Q16 = (_Float16*)Pout;       // [ 0, 4) MB
  _Float16* K16 = Q16 + E;               // [ 4, 8) MB
  _Float16* V16 = K16 + E;               // [ 8,12) MB
  _Float16* VT16 = V16 + E;              // [12,16) MB
  _Float16* Sc16 = VT16 + E;             // [16,48) MB: raw scores -> S16

  // ws (~280 MB available): x16, Wcat16, sigma, split-K partials
  _Float16* x16 = (_Float16*)d_ws;          // 4 MB
  _Float16* Wc16 = x16 + E;                 // 1.5 MB  [1536 x 512]
  float* sg = (float*)(Wc16 + 3 * DM * DM); // 16 KB
  float* Part = sg + 4096;                  // 24 MB (3 x 2M floats)

  const dim3 blk(256);

  // 1. pack x->fp16 + sigma + pack W->fp16 (fused)
  pack_sigma<<<2816, blk, 0, stream>>>(x, Wq, Wk, Wv, Ws, x16, Wc16, sg);

  // 2. fused QKV projection: [4096x1536] = x16 @ Wcat^T -> Q16,K16,V16 fp16
  mfma_f16<1><<<dim3(12, 32), blk, 0, stream>>>(
      x16, DM, Wc16, DM, DM, 1.0f, nullptr, 0, Q16, K16, V16, nullptr);

  // 3. V -> V^T fp16
  transpose16<<<dim3(16, 128), blk, 0, stream>>>(V16, VT16);

  // 4. raw scores fp16 = Q @ K^T / sqrt(D)
  mfma_f16<3><<<dim3(32, 32), blk, 0, stream>>>(
      Q16, DM, K16, DM, DM, 1.0f / sqrtf((float)DM), nullptr, N_TOK, Sc16,
      nullptr, nullptr, nullptr);

  // 5. softmax: Sc16 -> S fp32 + S16 fp16 (in place)
  softmax_kernel<<<N_TOK, blk, 0, stream>>>(Sc16, S);

  // 6. Z = S @ V, split-K x4 (z=0 -> Z, z=1..3 -> ws partials)
  mfma_f16<2><<<dim3(4, 32, 4), blk, 0, stream>>>(
      Sc16, N_TOK, VT16, N_TOK, N_TOK / 4, 1.0f, Z, DM, nullptr, nullptr,
      nullptr, Part);

  // 7. fused tail: P rows + Z reduction
  tail_kernel<<<4096 + 2048, blk, 0, stream>>>(sg, Pout, Z, Part);
}